// Round 10
// baseline (136.676 us; speedup 1.0000x reference)
//
#include <hip/hip_runtime.h>
#include <hip/hip_bf16.h>
#include <math.h>

typedef __attribute__((ext_vector_type(8))) __bf16 bf16x8;
typedef __attribute__((ext_vector_type(4))) __bf16 bf16x4;
typedef __attribute__((ext_vector_type(4))) float f32x4;

#define NTOK 4096
#define DHEAD 32
#define MBIAS 12.0f
#define QSCALE 0.2550316626f   // log2(e)/sqrt(32)

static __device__ __forceinline__ float fexp2(float x) {
    return __builtin_amdgcn_exp2f(x);
}

// ---------------- Kernel A: split x (fp32 [b][c][n]) -> xh/xl (bf16 [b*n][c]) ----------------
// One-time hi/lo split (8 MB traffic) so qkv's MFMA loop reads bf16 directly.
__global__ __launch_bounds__(256) void split_x_kernel(const float* __restrict__ x,
                                                      __bf16* __restrict__ xh,
                                                      __bf16* __restrict__ xl)
{
    const int tid  = threadIdx.x;
    const int w    = tid >> 6, lane = tid & 63;
    const int n    = blockIdx.x * 128 + (w >> 1) * 64 + lane;  // global n in [0,8192)
    const int c0   = (w & 1) * 64;
    const int b    = n >> 12;
    const int nn   = n & (NTOK - 1);
    const float* xp = x + ((size_t)b * 128 + c0) * NTOK + nn;
    __bf16* hp = xh + (size_t)n * 128 + c0;
    __bf16* lp = xl + (size_t)n * 128 + c0;
    for (int i0 = 0; i0 < 64; i0 += 8) {
        bf16x8 h8, l8;
        #pragma unroll
        for (int i = 0; i < 8; ++i) {
            float v = xp[(size_t)(i0 + i) * NTOK];
            __bf16 h = (__bf16)v;
            h8[i] = h;
            l8[i] = (__bf16)(v - (float)h);
        }
        *(bf16x8*)(hp + i0) = h8;
        *(bf16x8*)(lp + i0) = l8;
    }
}

// ---------------- Kernel B: QKV projection via split-bf16 MFMA ----------------
// wave tile = 16 o x 32 n ; grid 1536 = 6 otiles * 256 ntiles -> 6 blocks/CU.
__global__ __launch_bounds__(256, 4) void qkv_mfma_kernel(const __bf16* __restrict__ xh,
                                                          const __bf16* __restrict__ xl,
                                                          const float* __restrict__ w,
                                                          __bf16* __restrict__ Qo,
                                                          __bf16* __restrict__ Ko,
                                                          __bf16* __restrict__ Vo)
{
    const int bid   = blockIdx.x;        // 1536 = 6 otiles * 256 ntiles
    const int ot    = bid % 6;
    const int ntile = bid / 6;
    const int tid   = threadIdx.x;
    const int wv    = tid >> 6, lane = tid & 63;
    const int g = lane >> 4, ql = lane & 15;
    const int o0 = ot * 64 + wv * 16;
    const int n0 = ntile * 32;

    f32x4 acc[2] = {{0.f,0.f,0.f,0.f},{0.f,0.f,0.f,0.f}};

    #pragma unroll
    for (int kc = 0; kc < 4; ++kc) {
        const float* wp = w + (size_t)(o0 + ql) * 128 + kc * 32 + g * 8;
        f32x4 w0 = *(const f32x4*)wp;
        f32x4 w1 = *(const f32x4*)(wp + 4);
        bf16x8 wh, wl;
        #pragma unroll
        for (int i = 0; i < 4; ++i) {
            float v0 = w0[i], v1 = w1[i];
            __bf16 h0 = (__bf16)v0, h1 = (__bf16)v1;
            wh[i] = h0; wh[4 + i] = h1;
            wl[i] = (__bf16)(v0 - (float)h0);
            wl[4 + i] = (__bf16)(v1 - (float)h1);
        }
        #pragma unroll
        for (int nt = 0; nt < 2; ++nt) {
            const size_t bofs = (size_t)(n0 + nt * 16 + ql) * 128 + kc * 32 + g * 8;
            bf16x8 bh = *(const bf16x8*)(xh + bofs);
            bf16x8 bl = *(const bf16x8*)(xl + bofs);
            acc[nt] = __builtin_amdgcn_mfma_f32_16x16x32_bf16(wh, bh, acc[nt], 0, 0, 0);
            acc[nt] = __builtin_amdgcn_mfma_f32_16x16x32_bf16(wl, bh, acc[nt], 0, 0, 0);
            acc[nt] = __builtin_amdgcn_mfma_f32_16x16x32_bf16(wh, bl, acc[nt], 0, 0, 0);
        }
    }

    const int orow = o0 + 4 * g;   // +r ; branch uniform per wave (64-aligned o splits)
    #pragma unroll
    for (int nt = 0; nt < 2; ++nt) {
        const int ng = n0 + nt * 16 + ql;
        const int b = ng >> 12, nn = ng & (NTOK - 1);
        if (orow < 128) {
            const int h = orow >> 5, d0 = orow & 31;
            bf16x4 q4;
            #pragma unroll
            for (int r = 0; r < 4; ++r) q4[r] = (__bf16)(acc[nt][r] * QSCALE);
            *(bf16x4*)(Qo + ((size_t)(b * 4 + h) * NTOK + nn) * DHEAD + d0) = q4;
        } else if (orow < 256) {
            const int oo = orow - 128, h = oo >> 5, d0 = oo & 31;
            bf16x4 k4;
            #pragma unroll
            for (int r = 0; r < 4; ++r) k4[r] = (__bf16)acc[nt][r];
            *(bf16x4*)(Ko + ((size_t)(b * 4 + h) * NTOK + nn) * DHEAD + d0) = k4;
        } else {
            const int oo = orow - 256, h = oo >> 5, d0 = oo & 31;
            #pragma unroll
            for (int r = 0; r < 4; ++r)
                Vo[((size_t)(b * 4 + h) * DHEAD + d0 + r) * NTOK + nn] = (__bf16)acc[nt][r];
        }
    }
}

// ---------------- Kernel C: flash attention, static-max, 64 q/wave, 1-deep K/V prefetch ----------------
// 512 blocks x 512 thr (8 waves) = 2 blocks/CU, 4 waves/SIMD. Wave wv covers kv chunk
// [wv*512, wv*512+512); partials LDS-reduced across waves (additive: static MBIAS).
// Prefetch: issue iter t+1's 6 K/V loads BEFORE iter t's compute -> L2 latency hidden
// under ~300 cyc of MFMA+exp2 (R9 showed TLP alone leaves 80% stall).
// launch_bounds (512,4): VGPR cap 128 (~100 used) -> no spill (R6 lesson: never (512,8)).
__global__ __launch_bounds__(512, 4) void attn_kernel(const __bf16* __restrict__ Q,
                                                      const __bf16* __restrict__ K,
                                                      const __bf16* __restrict__ VT,
                                                      __bf16* __restrict__ oth,
                                                      __bf16* __restrict__ otl)
{
    __shared__ float red[8][2048];   // [wave][(qt*8+dt*4+r)*64 + lane]
    __shared__ float redl[8][64];    // [wave][qt*16+ql]
    const int bid = blockIdx.x;      // 512
    const int bh  = bid & 7;         // XCD-local head (round-robin dispatch)
    const int qg  = bid >> 3;        // [0,64)
    const int tid = threadIdx.x;
    const int wv  = tid >> 6;        // kv split
    const int lane = tid & 63;
    const int g = lane >> 4, ql = lane & 15;
    const __bf16* Qb = Q  + (size_t)bh * NTOK * DHEAD;
    const __bf16* Kb = K  + (size_t)bh * NTOK * DHEAD;
    const __bf16* Vb = VT + (size_t)bh * DHEAD * NTOK;
    const int q0 = qg * 64;

    bf16x8 qf[4];
    #pragma unroll
    for (int qt = 0; qt < 4; ++qt)
        qf[qt] = *(const bf16x8*)(Qb + (size_t)(q0 + qt * 16 + ql) * DHEAD + 8 * g);

    f32x4 acc[4][2] = {};        // [qt][dt] numerators of out^T
    float lsum[4] = {0.f, 0.f, 0.f, 0.f};
    const f32x4 mneg = {-MBIAS, -MBIAS, -MBIAS, -MBIAS};

    const __bf16* krow  = Kb + (size_t)ql * DHEAD + 8 * g;
    const __bf16* vrow0 = Vb + (size_t)ql * NTOK;
    const __bf16* vrow1 = Vb + (size_t)(16 + ql) * NTOK;

    const int base = wv * 512;
    // prime iter 0
    bf16x8 kf0 = *(const bf16x8*)(krow + (size_t)base * DHEAD);
    bf16x8 kf1 = *(const bf16x8*)(krow + (size_t)(base + 16) * DHEAD);
    bf16x4 va00 = *(const bf16x4*)(vrow0 + base + 4 * g);
    bf16x4 va01 = *(const bf16x4*)(vrow0 + base + 16 + 4 * g);
    bf16x4 va10 = *(const bf16x4*)(vrow1 + base + 4 * g);
    bf16x4 va11 = *(const bf16x4*)(vrow1 + base + 16 + 4 * g);

    for (int kv0 = base; kv0 < base + 512; kv0 += 32) {
        // prefetch next iter (wraps within chunk on last iter; values unused, in-bounds)
        const int kvn = base + ((kv0 + 32 - base) & 511);
        bf16x8 nkf0 = *(const bf16x8*)(krow + (size_t)kvn * DHEAD);
        bf16x8 nkf1 = *(const bf16x8*)(krow + (size_t)(kvn + 16) * DHEAD);
        bf16x4 nva00 = *(const bf16x4*)(vrow0 + kvn + 4 * g);
        bf16x4 nva01 = *(const bf16x4*)(vrow0 + kvn + 16 + 4 * g);
        bf16x4 nva10 = *(const bf16x4*)(vrow1 + kvn + 4 * g);
        bf16x4 nva11 = *(const bf16x4*)(vrow1 + kvn + 16 + 4 * g);

        // V^T A-fragments: slot j<4 -> kv0+4g+j ; j>=4 -> kv0+16+4g+(j-4) (matches S^T rows)
        bf16x8 vf0 = __builtin_shufflevector(va00, va01, 0,1,2,3,4,5,6,7);
        bf16x8 vf1 = __builtin_shufflevector(va10, va11, 0,1,2,3,4,5,6,7);

        #pragma unroll
        for (int qt = 0; qt < 4; ++qt) {
            f32x4 s0 = __builtin_amdgcn_mfma_f32_16x16x32_bf16(kf0, qf[qt], mneg, 0, 0, 0);
            f32x4 s1 = __builtin_amdgcn_mfma_f32_16x16x32_bf16(kf1, qf[qt], mneg, 0, 0, 0);
            bf16x8 pf;
            float ps = 0.f;
            #pragma unroll
            for (int r = 0; r < 4; ++r) {
                float e0 = fexp2(s0[r]);
                float e1 = fexp2(s1[r]);
                ps += e0 + e1;
                pf[r]     = (__bf16)e0;
                pf[4 + r] = (__bf16)e1;
            }
            lsum[qt] += ps;
            acc[qt][0] = __builtin_amdgcn_mfma_f32_16x16x32_bf16(vf0, pf, acc[qt][0], 0, 0, 0);
            acc[qt][1] = __builtin_amdgcn_mfma_f32_16x16x32_bf16(vf1, pf, acc[qt][1], 0, 0, 0);
        }

        kf0 = nkf0; kf1 = nkf1;
        va00 = nva00; va01 = nva01; va10 = nva10; va11 = nva11;
    }

    // per-wave l: reduce across the 4 g-groups (lanes l, l^16, l^32, l^48)
    #pragma unroll
    for (int qt = 0; qt < 4; ++qt) {
        lsum[qt] += __shfl_xor(lsum[qt], 16);
        lsum[qt] += __shfl_xor(lsum[qt], 32);
    }

    // stage 1: per-wave partials to LDS (lane-consecutive -> conflict-free)
    #pragma unroll
    for (int qt = 0; qt < 4; ++qt)
        #pragma unroll
        for (int dt = 0; dt < 2; ++dt)
            #pragma unroll
            for (int r = 0; r < 4; ++r)
                red[wv][(qt * 8 + dt * 4 + r) * 64 + lane] = acc[qt][dt][r];
    if (lane < 16) {
        #pragma unroll
        for (int qt = 0; qt < 4; ++qt) redl[wv][qt * 16 + ql] = lsum[qt];
    }
    __syncthreads();

    // stage 2: each thread owns 4 of the 2048 elements; sum across 8 waves
    {
        const int e0 = tid * 4;
        float s0 = 0.f, s1 = 0.f, s2 = 0.f, s3 = 0.f;
        #pragma unroll
        for (int w = 0; w < 8; ++w) {
            s0 += red[w][e0];     s1 += red[w][e0 + 1];
            s2 += red[w][e0 + 2]; s3 += red[w][e0 + 3];
        }
        red[0][e0] = s0; red[0][e0 + 1] = s1; red[0][e0 + 2] = s2; red[0][e0 + 3] = s3;
        if (tid < 64) {
            float s = 0.f;
            #pragma unroll
            for (int w = 0; w < 8; ++w) s += redl[w][tid];
            redl[0][tid] = s;
        }
    }
    __syncthreads();

    // stage 3: waves 0..3 normalize + hi/lo split + store bf16 out token-major [b][n][128]
    if (wv < 4) {
        const int qt = wv;
        const int b = bh >> 2, h = bh & 3;
        const int n = q0 + qt * 16 + ql;
        const float inv = 1.0f / redl[0][qt * 16 + ql];
        __bf16* hp = oth + ((size_t)b * NTOK + n) * 128 + h * 32;
        __bf16* lp = otl + ((size_t)b * NTOK + n) * 128 + h * 32;
        #pragma unroll
        for (int dt = 0; dt < 2; ++dt) {
            bf16x4 h4, l4;
            #pragma unroll
            for (int r = 0; r < 4; ++r) {
                float v = red[0][(qt * 8 + dt * 4 + r) * 64 + lane] * inv;
                __bf16 hh = (__bf16)v;
                h4[r] = hh;
                l4[r] = (__bf16)(v - (float)hh);
            }
            *(bf16x4*)(hp + dt * 16 + 4 * g) = h4;
            *(bf16x4*)(lp + dt * 16 + 4 * g) = l4;
        }
    }
}

// ---------------- Kernel D: output projection via split-bf16 MFMA + bias ----------------
// wave tile = 16 o x 16 n ; grid 1024 -> 4 blocks/CU. Inputs already bf16 hi/lo.
__global__ __launch_bounds__(256, 4) void out_mfma_kernel(const __bf16* __restrict__ oh,
                                                          const __bf16* __restrict__ ol,
                                                          const float* __restrict__ w,
                                                          const float* __restrict__ bias,
                                                          float* __restrict__ y)
{
    const int bid   = blockIdx.x;        // 1024 = 2 otiles * 512 ntiles
    const int otile = bid & 1;
    const int ntile = bid >> 1;
    const int tid   = threadIdx.x;
    const int wv    = tid >> 6, lane = tid & 63;
    const int g = lane >> 4, ql = lane & 15;
    const int o0 = otile * 64 + wv * 16;
    const int n0 = ntile * 16;

    f32x4 acc = {0.f,0.f,0.f,0.f};

    #pragma unroll
    for (int kc = 0; kc < 4; ++kc) {
        const float* wp = w + (size_t)(o0 + ql) * 128 + kc * 32 + g * 8;
        f32x4 w0 = *(const f32x4*)wp;
        f32x4 w1 = *(const f32x4*)(wp + 4);
        bf16x8 wh, wl;
        #pragma unroll
        for (int i = 0; i < 4; ++i) {
            float v0 = w0[i], v1 = w1[i];
            __bf16 h0 = (__bf16)v0, h1 = (__bf16)v1;
            wh[i] = h0; wh[4 + i] = h1;
            wl[i] = (__bf16)(v0 - (float)h0);
            wl[4 + i] = (__bf16)(v1 - (float)h1);
        }
        const size_t bofs = (size_t)(n0 + ql) * 128 + kc * 32 + g * 8;
        bf16x8 bh = *(const bf16x8*)(oh + bofs);
        bf16x8 bl = *(const bf16x8*)(ol + bofs);
        acc = __builtin_amdgcn_mfma_f32_16x16x32_bf16(wh, bh, acc, 0, 0, 0);
        acc = __builtin_amdgcn_mfma_f32_16x16x32_bf16(wl, bh, acc, 0, 0, 0);
        acc = __builtin_amdgcn_mfma_f32_16x16x32_bf16(wh, bl, acc, 0, 0, 0);
    }

    const int orow = o0 + 4 * g;
    const int ng = n0 + ql;
    const int b = ng >> 12, nn = ng & (NTOK - 1);
    #pragma unroll
    for (int r = 0; r < 4; ++r)
        y[((size_t)b * 128 + orow + r) * NTOK + nn] = acc[r] + bias[orow + r];
}

extern "C" void kernel_launch(void* const* d_in, const int* in_sizes, int n_in,
                              void* d_out, int out_size, void* d_ws, size_t ws_size,
                              hipStream_t stream) {
    const float* x     = (const float*)d_in[0];
    const float* w_qkv = (const float*)d_in[1];
    const float* w_out = (const float*)d_in[2];
    const float* b_out = (const float*)d_in[3];
    float* y = (float*)d_out;

    // ws layout (14 MB): xh 2M | xl 2M | Q 2M | K 2M | VT 2M | oth 2M | otl 2M
    char* ws = (char*)d_ws;
    __bf16* xh  = (__bf16*)(ws);
    __bf16* xl  = (__bf16*)(ws + (size_t)2 * 1024 * 1024);
    __bf16* Qb  = (__bf16*)(ws + (size_t)4 * 1024 * 1024);
    __bf16* Kb  = (__bf16*)(ws + (size_t)6 * 1024 * 1024);
    __bf16* Vb  = (__bf16*)(ws + (size_t)8 * 1024 * 1024);
    __bf16* oth = (__bf16*)(ws + (size_t)10 * 1024 * 1024);
    __bf16* otl = (__bf16*)(ws + (size_t)12 * 1024 * 1024);

    hipLaunchKernelGGL(split_x_kernel, dim3(64), dim3(256), 0, stream, x, xh, xl);
    hipLaunchKernelGGL(qkv_mfma_kernel, dim3(1536), dim3(256), 0, stream, xh, xl, w_qkv, Qb, Kb, Vb);
    hipLaunchKernelGGL(attn_kernel, dim3(512), dim3(512), 0, stream, Qb, Kb, Vb, oth, otl);
    hipLaunchKernelGGL(out_mfma_kernel, dim3(1024), dim3(256), 0, stream, oth, otl, w_out, b_out, y);
}